// Round 13
// baseline (479.456 us; speedup 1.0000x reference)
//
#include <hip/hip_runtime.h>
#include <type_traits>

#define N_TOK 65536
#define K_CODE 8192
#define D_DIM 64

constexpr float DECAY = 0.9f;
constexpr float OMD = 0.1f;   // 1 - DECAY
constexpr float EPS = 1e-5f;

// ---- output layout (floats), per reference return order ----
constexpr int OUT_QE = 0;
constexpr int OUT_W  = 1;
constexpr int OUT_CS = 1 + K_CODE * D_DIM;
constexpr int OUT_EA = OUT_CS + K_CODE;

// ---- workspace layout (floats) ----
constexpr int WS_QE     = 0;
constexpr int WS_BAR0   = 8;                            // uint barrier counter (phase P->A)
constexpr int WS_BAR1   = 9;                            // uint barrier counter (phase A->F)
constexpr int WS_NSUM   = 16;                           // 8 slots, stride 32 floats (128B apart)
constexpr int WS_COUNTS = 16 + 8 * 32;                  // 272 (header ends here)
constexpr int WS_EMBSUM = WS_COUNTS + K_CODE;
constexpr int WS_WHI    = WS_EMBSUM + K_CODE * D_DIM;   // ushort[K*64] bf16 hi, XOR-swizzled
constexpr int WS_WLO    = WS_WHI + K_CODE * D_DIM / 2;  // ushort[K*64] bf16 lo, XOR-swizzled
constexpr int WS_CNF    = WS_WLO + K_CODE * D_DIM / 2;  // float[K]: ||c||^2 + 64 (exact f32)

typedef __attribute__((ext_vector_type(16))) float floatx16;
typedef __attribute__((ext_vector_type(8)))  short short8;
typedef __attribute__((ext_vector_type(8)))  __bf16 bf16x8;

// SFINAE hedge: mfma bf16 builtin takes v8bf16 on newer clang, v8i16 on older.
template <typename T, typename = void> struct mfma_takes : std::false_type {};
template <typename T>
struct mfma_takes<T, std::void_t<decltype(__builtin_amdgcn_mfma_f32_32x32x16_bf16(
    std::declval<T>(), std::declval<T>(), std::declval<floatx16>(), 0, 0, 0))>>
    : std::true_type {};

__device__ __forceinline__ floatx16 MFMA(short8 a, short8 b, floatx16 c) {
  if constexpr (mfma_takes<bf16x8>::value) {
    return __builtin_amdgcn_mfma_f32_32x32x16_bf16(
        __builtin_bit_cast(bf16x8, a), __builtin_bit_cast(bf16x8, b), c, 0, 0, 0);
  } else {
    return __builtin_amdgcn_mfma_f32_32x32x16_bf16(a, b, c, 0, 0, 0);
  }
}

__device__ __forceinline__ unsigned short bf16rne(float x) {
  unsigned int u = __float_as_uint(x);
  return (unsigned short)((u + 0x7FFFu + ((u >> 16) & 1u)) >> 16);
}

// async global->LDS 16B DMA (HW writes LDS at wave-uniform dst + lane*16)
__device__ __forceinline__ void gload_lds16(const unsigned short* g, unsigned short* l) {
#if defined(__has_builtin) && __has_builtin(__builtin_amdgcn_global_load_lds)
  typedef __attribute__((address_space(1))) void gvoid;
  typedef __attribute__((address_space(3))) void lvoid;
  __builtin_amdgcn_global_load_lds((gvoid*)g, (lvoid*)l, 16, 0, 0);
#else
  *(uint4*)l = *(const uint4*)g;   // sync fallback (builtin exists on gfx950)
#endif
}

// ---------------------------------------------------------------------------
// Software grid barrier (graph-capturable; R12's hipLaunchCooperativeKernel
// silently failed under the harness's graph capture — out stayed zero).
// SAFE ONLY because co-residency is exact: grid 512 = capacity 2 blocks/CU x
// 256 CU (16 waves/CU at launch_bounds(512,4); VGPR 56<=64; LDS 2x66KB<=160K)
// => all blocks resident from dispatch, every block reaches the barrier.
// Release: __threadfence() (agent-scope, L2-invalidating on gfx940+ — the
// same mechanism grid.sync uses) before the device-scope arrival atomicAdd
// [m20]. Acquire: agent-scope atomic spin-load + __threadfence() after.
// Counters live in the header, re-zeroed by the per-launch memset.
__device__ __forceinline__ void grid_barrier(float* ws, int slot, unsigned nblk) {
  __syncthreads();
  if (threadIdx.x == 0) {
    unsigned int* ctr = (unsigned int*)ws + slot;
    __threadfence();                      // release prior writes device-wide
    atomicAdd(ctr, 1u);
    while (__hip_atomic_load(ctr, __ATOMIC_ACQUIRE, __HIP_MEMORY_SCOPE_AGENT) < nblk) {
      __builtin_amdgcn_s_sleep(8);
    }
    __threadfence();                      // acquire
  }
  __syncthreads();
}

// ---------------------------------------------------------------------------
// R13: single fused kernel (prep | grid_barrier | argmin | grid_barrier |
// finalize), regular launch. Phase A is R11 byte-identical (206.8us body;
// converged: R1 vmcnt, R5 role-split, R9 chain-split, R10 full read-ahead
// all null; R11 sprinkle +3.4%). Fusion targets the ~56-64us total-minus-
// argmin gap (launch/drain boundaries + P/F work).
//
// Phase A pipeline safety (R4/R10 proofs): each fenced region issues exactly
// {2 DMA, 1 cnf} = 3 vm ops; vmcnt(3) at region s retires region s-1's ops
// incl. DMA(s+1); barrier(s) publishes buf (s+1)&3 block-wide. DMA(s+2)
// issues 2 stages ahead; 4 bufs => overwriting DMA is 2+ barriers after the
// last read. Branchless wrap keeps vm-op counts uniform.
__global__ __launch_bounds__(512, 4) void vq_fused(
    const float* __restrict__ z, const float* __restrict__ wgt,
    const float* __restrict__ cs, const float* __restrict__ ea,
    float* __restrict__ ws, float* __restrict__ out)
{
  __shared__ __align__(16) unsigned short Wbuf[2][4][2][32 * 64]; // [half][buf][plane]
  __shared__ float mind_s[2][128];
  __shared__ int   tok_s[2][128];
  __shared__ float csp[16];

  const int tid  = threadIdx.x;
  const int w    = tid >> 6;    // wave 0..7
  const int lane = tid & 63;
  const int bid  = blockIdx.x;  // 0..511

  // ======================= phase P: prep (16 codes/block) ==================
  {
    // zero counts + embsum (1024 embsum floats/block; first 16 blocks: counts)
    ws[WS_EMBSUM + bid * 1024 + tid] = 0.0f;
    ws[WS_EMBSUM + bid * 1024 + 512 + tid] = 0.0f;
    if (bid < 16) ws[WS_COUNTS + bid * 512 + tid] = 0.0f;

    unsigned short* whi_w = (unsigned short*)(ws + WS_WHI);
    unsigned short* wlo_w = (unsigned short*)(ws + WS_WLO);
#pragma unroll
    for (int sub = 0; sub < 2; ++sub) {
      const int k = bid * 16 + w * 2 + sub;
      const int d = lane;
      const float v = wgt[(size_t)k * D_DIM + d];
      const unsigned short hb = bf16rne(v);
      const float hf = __uint_as_float((unsigned int)hb << 16);
      const unsigned short lb = bf16rne(v - hf);
      const int pos = k * D_DIM + (((d >> 3) ^ (k & 7)) * 8) + (d & 7);
      whi_w[pos] = hb;
      wlo_w[pos] = lb;
      float s = v * v;
#pragma unroll
      for (int mm = 32; mm >= 1; mm >>= 1) s += __shfl_xor(s, mm);
      if (d == 0) {
        (ws + WS_CNF)[k] = s + 64.0f;
        csp[w * 2 + sub] = cs[k];
      }
    }
    __syncthreads();
    if (tid == 0) {
      float t = 0.f;
#pragma unroll
      for (int i = 0; i < 16; ++i) t += csp[i];
      atomicAdd(ws + WS_NSUM + ((bid & 7) << 5), DECAY * t);
    }
  }

  grid_barrier(ws, WS_BAR0, 512u);  // whi/wlo/cnf + zeroed counts/embsum visible

  // ======================= phase A: argmin (R11 body) ======================
  {
    const int m    = lane & 31;   // A row (token) / B col (code) in tile
    const int h    = lane >> 5;   // k-half selector
    const int tg   = w & 3;       // token group (32 tokens)
    const int hw   = w >> 2;      // code half (4096 codes)
    const int tb   = bid * 128;

    const unsigned short* whi = (const unsigned short*)(ws + WS_WHI);
    const unsigned short* wlo = (const unsigned short*)(ws + WS_WLO);
    const float*          cnf = ws + WS_CNF;

    // ---- A fragments: bf16 hi/lo split of -2*z for this wave's 32 rows ----
    short8 ah[4], al[4];
    float znorm = 0.f;
    {
      const float* zrow = z + (size_t)(tb + tg * 32 + m) * D_DIM + 8 * h;
#pragma unroll
      for (int s4 = 0; s4 < 4; ++s4) {
        const float4 v0 = *(const float4*)(zrow + 16 * s4);
        const float4 v1 = *(const float4*)(zrow + 16 * s4 + 4);
        const float vals[8] = {v0.x, v0.y, v0.z, v0.w, v1.x, v1.y, v1.z, v1.w};
#pragma unroll
        for (int j = 0; j < 8; ++j) {
          const float x = vals[j];
          znorm += x * x;
          const float y = -2.0f * x;
          const unsigned short hb = bf16rne(y);
          const float hf = __uint_as_float((unsigned int)hb << 16);
          const unsigned short lb = bf16rne(y - hf);
          ah[s4][j] = (short)hb;
          al[s4][j] = (short)lb;
        }
      }
      znorm += __shfl_xor(znorm, 32);   // other k-half of the same token row
    }

    float kmin[16];
#pragma unroll
    for (int r = 0; r < 16; ++r) kmin[r] = 3.4e38f;

    // ---- DMA staging: stage = 16 KB as 16 x 1KB segments; wave w moves
    // segments 2w, 2w+1. seg t: half=t>>3, plane=(t>>2)&1, quarter=t&3.
    auto issueStage = [&](int sIdx, int bufIdx) {
#pragma unroll
      for (int i = 0; i < 2; ++i) {
        const int t = w * 2 + i;
        const int half = t >> 3, plane = (t >> 2) & 1, seg = t & 3;
        const unsigned short* src = (plane ? wlo : whi)
            + ((size_t)half * 4096 + (size_t)sIdx * 32) * D_DIM + seg * 512 + lane * 8;
        unsigned short* dst = &Wbuf[half][bufIdx][plane][seg * 512];  // wave-uniform
        gload_lds16(src, dst);
      }
    };

    // precomputed per-lane B read offsets (shorts) into the pre-swizzled rows
    int xoff[4];
#pragma unroll
    for (int s4 = 0; s4 < 4; ++s4) xoff[s4] = ((2 * s4 + h) ^ (m & 7)) * 8;
    const int mrow = m * 64;
    const int cbase = hw * 4096;

#define RDH(BUF, I) (*(const short8*)&Wbuf[hw][(BUF)][0][mrow + xoff[(I)]])
#define RDL(BUF, I) (*(const short8*)&Wbuf[hw][(BUF)][1][mrow + xoff[(I)]])

    // ---- prologue: 2 stages of DMA, drain once, prime bh+bl <- stage 0 ----
    issueStage(0, 0);
    issueStage(1, 1);
    float cn_cur = cnf[cbase + m];
    asm volatile("s_waitcnt vmcnt(0)" ::: "memory");
    __builtin_amdgcn_s_barrier();
    asm volatile("" ::: "memory");

    short8 bh0 = RDH(0, 0), bh1 = RDH(0, 1), bh2 = RDH(0, 2), bh3 = RDH(0, 3);
    short8 bl0 = RDL(0, 0), bl1 = RDL(0, 1), bl2 = RDL(0, 2), bl3 = RDL(0, 3);

    for (int s = 0; s < 128; ++s) {
      // region s: issue exactly {2 DMA, 1 cnf} = 3 vm ops (branchless wrap
      // keeps the count uniform; tail DMAs land in dead buffers)
      issueStage((s + 2) & 127, (s + 2) & 3);
      const float cn_next = cnf[cbase + ((s + 1) & 127) * 32 + m];
      asm volatile("s_waitcnt vmcnt(3)" ::: "memory");
      __builtin_amdgcn_s_barrier();
      asm volatile("" ::: "memory");

      const int nb = (s + 1) & 3;

      floatx16 acc;
#pragma unroll
      for (int r = 0; r < 16; ++r) acc[r] = cn_cur;

      // pairwise plane products: bh_i dies after its 2 MFMAs -> its s+1
      // replacement read issues immediately (WAR-pinned, sprinkled through
      // the MFMA phase). bl_i dies after 1 MFMA; same pattern.
      acc = MFMA(ah[0], bh0, acc);
      acc = MFMA(al[0], bh0, acc);
      bh0 = RDH(nb, 0);
      acc = MFMA(ah[1], bh1, acc);
      acc = MFMA(al[1], bh1, acc);
      bh1 = RDH(nb, 1);
      acc = MFMA(ah[2], bh2, acc);
      acc = MFMA(al[2], bh2, acc);
      bh2 = RDH(nb, 2);
      acc = MFMA(ah[3], bh3, acc);
      acc = MFMA(al[3], bh3, acc);
      bh3 = RDH(nb, 3);
      acc = MFMA(ah[0], bl0, acc);
      bl0 = RDL(nb, 0);
      acc = MFMA(ah[1], bl1, acc);
      bl1 = RDL(nb, 1);
      acc = MFMA(ah[2], bl2, acc);
      bl2 = RDL(nb, 2);
      acc = MFMA(ah[3], bl3, acc);
      bl3 = RDL(nb, 3);

      // packed-key argmin: acc[r] > 0; low byte := stage id
#pragma unroll
      for (int r = 0; r < 16; ++r) {
        kmin[r] = fminf(kmin[r],
            __uint_as_float((__float_as_uint(acc[r]) & 0xFFFFFF00u) | (unsigned)s));
      }
      cn_cur = cn_next;
    }
#undef RDH
#undef RDL

    // ---- reduce over the 32 code-cols per row, carrying origin lane ----
#pragma unroll
    for (int r = 0; r < 16; ++r) {
      float kv = kmin[r];
      int mo = m;
#pragma unroll
      for (int mm = 1; mm < 32; mm <<= 1) {
        const float ov = __shfl_xor(kv, mm);
        const int   om = __shfl_xor(mo, mm);
        if (ov < kv || (ov == kv && om < mo)) { kv = ov; mo = om; }
      }
      // C/D layout: row = (r&3) + 8*(r>>2) + 4*h. One writer lane per row.
      const int mr = (r & 3) + 8 * (r >> 2) + 4 * h;
      if (m == mr) {
        const unsigned int kb = __float_as_uint(kv);
        tok_s[hw][tg * 32 + mr] = hw * 4096 + (int)(kb & 0xFFu) * 32 + mo;
        mind_s[hw][tg * 32 + mr] =
            __uint_as_float(kb & 0xFFFFFF00u) - 64.0f + znorm;
      }
    }
    __syncthreads();

    float* counts = ws + WS_COUNTS;
    float* embsum = ws + WS_EMBSUM;

    // merge code-halves (strict '<' keeps half0 on ties), qe partial + counts
    if (tid < 128) {
      const float d0 = mind_s[0][tid], d1 = mind_s[1][tid];
      const int   i0 = tok_s[0][tid],  i1 = tok_s[1][tid];
      const bool t1 = d1 < d0;
      const float dm = t1 ? d1 : d0;
      const int   im = t1 ? i1 : i0;
      tok_s[0][tid] = im;
      float qe = dm;
#pragma unroll
      for (int mm = 32; mm >= 1; mm >>= 1) qe += __shfl_xor(qe, mm);
      if ((tid & 63) == 0) atomicAdd(ws + WS_QE, qe);
      atomicAdd(&counts[im], 1.0f);
    }
    __syncthreads();

    // segment-sum of z: wave-coalesced atomics (64 consecutive floats/instr)
#pragma unroll 4
    for (int t = 0; t < 16; ++t) {
      const int row = w * 16 + t;
      const int tk = tok_s[0][row];
      const float zv = z[(size_t)(tb + row) * D_DIM + lane];
      atomicAdd(&embsum[(size_t)tk * D_DIM + lane], zv);
    }
  }

  grid_barrier(ws, WS_BAR1, 512u);  // counts/embsum/QE complete device-wide

  // ======================= phase F: finalize (2 elems/thread) ==============
  {
    float n = OMD * (float)N_TOK;
#pragma unroll
    for (int i = 0; i < 8; ++i) n += ws[WS_NSUM + (i << 5)];
    const float inv_den = n / (n + K_CODE * EPS);
#pragma unroll
    for (int j = 0; j < 2; ++j) {
      const int idx = bid * 1024 + j * 512 + tid;   // over K*D
      const int k = idx >> 6;
      const float ncs = cs[k] * DECAY + OMD * ws[WS_COUNTS + k];
      const float nea = ea[idx] * DECAY + OMD * ws[WS_EMBSUM + idx];
      out[OUT_EA + idx] = nea;
      const float sm = (ncs + EPS) * inv_den;
      out[OUT_W + idx] = nea / sm;
      if ((idx & 63) == 0) out[OUT_CS + k] = ncs;
    }
    if (bid == 0 && tid == 0) out[OUT_QE] = ws[WS_QE] * (1.0f / N_TOK);
  }
}

// ---------------------------------------------------------------------------
extern "C" void kernel_launch(void* const* d_in, const int* in_sizes, int n_in,
                              void* d_out, int out_size, void* d_ws, size_t ws_size,
                              hipStream_t stream) {
  const float* z  = (const float*)d_in[0];
  const float* w  = (const float*)d_in[1];
  const float* cs = (const float*)d_in[2];
  const float* ea = (const float*)d_in[3];
  float* out = (float*)d_out;
  float* ws  = (float*)d_ws;

  // header only (QE + barrier counters + NSUM); counts/embsum zeroed in P
  (void)hipMemsetAsync(d_ws, 0, (size_t)WS_COUNTS * sizeof(float), stream);

  vq_fused<<<512, 512, 0, stream>>>(z, w, cs, ea, ws, out);
}

// Round 15
// 276.277 us; speedup vs baseline: 1.7354x; 1.7354x over previous
//
#include <hip/hip_runtime.h>
#include <type_traits>

#define N_TOK 65536
#define K_CODE 8192
#define D_DIM 64

constexpr float DECAY = 0.9f;
constexpr float OMD = 0.1f;   // 1 - DECAY
constexpr float EPS = 1e-5f;

// ---- output layout (floats), per reference return order ----
constexpr int OUT_QE = 0;
constexpr int OUT_W  = 1;
constexpr int OUT_CS = 1 + K_CODE * D_DIM;
constexpr int OUT_EA = OUT_CS + K_CODE;

// ---- workspace layout (floats) ----
constexpr int WS_QE     = 0;
constexpr int WS_NSUM   = 16;                           // 8 slots, stride 32 floats (128B apart)
constexpr int WS_COUNTS = 16 + 8 * 32;                  // 272 (header ends here)
constexpr int WS_EMBSUM = WS_COUNTS + K_CODE;
constexpr int WS_WHI    = WS_EMBSUM + K_CODE * D_DIM;   // ushort[K*64] bf16 hi, XOR-swizzled
constexpr int WS_WLO    = WS_WHI + K_CODE * D_DIM / 2;  // ushort[K*64] bf16 lo, XOR-swizzled
constexpr int WS_CNF    = WS_WLO + K_CODE * D_DIM / 2;  // float[K]: ||c||^2 + 64 (exact f32)

typedef __attribute__((ext_vector_type(16))) float floatx16;
typedef __attribute__((ext_vector_type(8)))  short short8;
typedef __attribute__((ext_vector_type(8)))  __bf16 bf16x8;

// SFINAE hedge: mfma bf16 builtin takes v8bf16 on newer clang, v8i16 on older.
template <typename T, typename = void> struct mfma_takes : std::false_type {};
template <typename T>
struct mfma_takes<T, std::void_t<decltype(__builtin_amdgcn_mfma_f32_32x32x16_bf16(
    std::declval<T>(), std::declval<T>(), std::declval<floatx16>(), 0, 0, 0))>>
    : std::true_type {};

__device__ __forceinline__ floatx16 MFMA(short8 a, short8 b, floatx16 c) {
  if constexpr (mfma_takes<bf16x8>::value) {
    return __builtin_amdgcn_mfma_f32_32x32x16_bf16(
        __builtin_bit_cast(bf16x8, a), __builtin_bit_cast(bf16x8, b), c, 0, 0, 0);
  } else {
    return __builtin_amdgcn_mfma_f32_32x32x16_bf16(a, b, c, 0, 0, 0);
  }
}

__device__ __forceinline__ unsigned short bf16rne(float x) {
  unsigned int u = __float_as_uint(x);
  return (unsigned short)((u + 0x7FFFu + ((u >> 16) & 1u)) >> 16);
}

// async global->LDS 16B DMA (HW writes LDS at wave-uniform dst + lane*16)
__device__ __forceinline__ void gload_lds16(const unsigned short* g, unsigned short* l) {
#if defined(__has_builtin) && __has_builtin(__builtin_amdgcn_global_load_lds)
  typedef __attribute__((address_space(1))) void gvoid;
  typedef __attribute__((address_space(3))) void lvoid;
  __builtin_amdgcn_global_load_lds((gvoid*)g, (lvoid*)l, 16, 0, 0);
#else
  *(uint4*)l = *(const uint4*)g;   // sync fallback (builtin exists on gfx950)
#endif
}

// ---------------------------------------------------------------------------
// Split W into bf16 hi/lo, stored XOR-SWIZZLED (granule g -> g^(k&7), stride
// 64 shorts) so global_load_lds's linear copy lands conflict-managed in LDS.
// Store ||c||^2 + 64 as exact f32. NSUM: one atomic per block into 8
// line-spread slots. Folds counts/embsum zeroing in (host memset = header
// only; stream order memset -> prep -> argmin keeps NSUM atomics safe).
// R15 == R11 verbatim (R14's hi-only codebook failed accuracy: weight
// output is count-sensitive for small-cluster codes; the lo-plane is
// load-bearing. R12/R13 fusion closed: coop launch not graph-capturable,
// software barrier pays 2x in per-block fence traffic.)
__global__ void vq_prep(const float* __restrict__ w, const float* __restrict__ cs,
                        float* __restrict__ ws) {
  const int tid = threadIdx.x;
  const int gid = blockIdx.x * 256 + tid;   // 0 .. K*D-1
  ws[WS_EMBSUM + gid] = 0.0f;
  if (gid < K_CODE) ws[WS_COUNTS + gid] = 0.0f;

  const int d = tid & 63;                 // dim
  const int kw = tid >> 6;                // 0..3
  const int k = blockIdx.x * 4 + kw;
  const float v = w[(size_t)k * D_DIM + d];
  const unsigned short h = bf16rne(v);
  const float hf = __uint_as_float((unsigned int)h << 16);
  const unsigned short l = bf16rne(v - hf);
  unsigned short* whi = (unsigned short*)(ws + WS_WHI);
  unsigned short* wlo = (unsigned short*)(ws + WS_WLO);
  const int pos = k * D_DIM + (((d >> 3) ^ (k & 7)) * 8) + (d & 7);
  whi[pos] = h;
  wlo[pos] = l;
  float s = v * v;
#pragma unroll
  for (int m = 32; m >= 1; m >>= 1) s += __shfl_xor(s, m);
  __shared__ float csp[4];
  if (d == 0) {
    (ws + WS_CNF)[k] = s + 64.0f;
    csp[kw] = cs[k];
  }
  __syncthreads();
  if (tid == 0) {
    atomicAdd(ws + WS_NSUM + ((blockIdx.x & 7) << 5),
              DECAY * (csp[0] + csp[1] + csp[2] + csp[3]));
  }
}

// ---------------------------------------------------------------------------
// Fused split-bf16 MFMA distance + argmin + segment-sum scatter.
//
// R11 body (converged): sprinkled WAR-freeing reads — pairwise plane
// products (ah_i*bh_i, al_i*bh_i) so bh_i dies after 2 MFMAs and its s+1
// replacement ds_read issues right there, distributed through the MFMA
// phase; bl_i dies after 1 MFMA, same pattern. No setprio (m190: negative
// on this structure). Wall 1939 cyc/block-stage = 0.89x pipe-demand sum
// (LDS 1150 + MFMA 775 + VALU 250) — structural limit; levers measured
// null/negative: vmcnt depth (R1), role-split (R5), tokens/wave (R6-R8,
// register wall), chain-split (R7/R9), full read-ahead (R10), fusion
// (R12/R13), precision cut (R14).
//
// Block = 8 waves = 4 token-groups(32 tok) x 2 code-halves; 128 tok/block;
// grid 512 = 2 blocks/CU = 16 waves/CU = 4 waves/SIMD (proven cell).
//
// Pipeline safety (R4/R10 proofs): each fenced region issues exactly
// {2 DMA, 1 cnf} = 3 vm ops; vmcnt(3) at region s retires region s-1's ops
// incl. DMA(s+1); barrier(s) publishes buf (s+1)&3 block-wide — the
// guarantee every bh/bl(s+1) read relies on. DMA(s+2) issues 2 stages
// ahead. 4 bufs: buf (s+1)&3 is read during stage s; its overwriting DMA
// issues at region s+3, 2+ barriers later => no race. Branchless wrap
// keeps vm-op counts uniform (tail reads/DMAs land in dead buffers).
__global__ __launch_bounds__(512, 4) void vq_argmin(
    const float* __restrict__ z, float* __restrict__ ws)
{
  __shared__ __align__(16) unsigned short Wbuf[2][4][2][32 * 64]; // [half][buf][plane]
  __shared__ float mind_s[2][128];
  __shared__ int   tok_s[2][128];

  const int tid  = threadIdx.x;
  const int w    = tid >> 6;    // wave 0..7
  const int lane = tid & 63;
  const int m    = lane & 31;   // A row (token) / B col (code) in tile
  const int h    = lane >> 5;   // k-half selector
  const int tg   = w & 3;       // token group (32 tokens)
  const int hw   = w >> 2;      // code half (4096 codes)
  const int tb   = blockIdx.x * 128;

  const unsigned short* whi = (const unsigned short*)(ws + WS_WHI);
  const unsigned short* wlo = (const unsigned short*)(ws + WS_WLO);
  const float*          cnf = ws + WS_CNF;

  // ---- A fragments: bf16 hi/lo split of -2*z for this wave's 32 rows ----
  short8 ah[4], al[4];
  float znorm = 0.f;
  {
    const float* zrow = z + (size_t)(tb + tg * 32 + m) * D_DIM + 8 * h;
#pragma unroll
    for (int s4 = 0; s4 < 4; ++s4) {
      const float4 v0 = *(const float4*)(zrow + 16 * s4);
      const float4 v1 = *(const float4*)(zrow + 16 * s4 + 4);
      const float vals[8] = {v0.x, v0.y, v0.z, v0.w, v1.x, v1.y, v1.z, v1.w};
#pragma unroll
      for (int j = 0; j < 8; ++j) {
        const float x = vals[j];
        znorm += x * x;
        const float y = -2.0f * x;
        const unsigned short hb = bf16rne(y);
        const float hf = __uint_as_float((unsigned int)hb << 16);
        const unsigned short lb = bf16rne(y - hf);
        ah[s4][j] = (short)hb;
        al[s4][j] = (short)lb;
      }
    }
    znorm += __shfl_xor(znorm, 32);   // other k-half of the same token row
  }

  float kmin[16];
#pragma unroll
  for (int r = 0; r < 16; ++r) kmin[r] = 3.4e38f;

  // ---- DMA staging: stage = 16 KB as 16 x 1KB segments; wave w moves
  // segments 2w, 2w+1. seg t: half=t>>3, plane=(t>>2)&1, quarter=t&3.
  auto issueStage = [&](int sIdx, int bufIdx) {
#pragma unroll
    for (int i = 0; i < 2; ++i) {
      const int t = w * 2 + i;
      const int half = t >> 3, plane = (t >> 2) & 1, seg = t & 3;
      const unsigned short* src = (plane ? wlo : whi)
          + ((size_t)half * 4096 + (size_t)sIdx * 32) * D_DIM + seg * 512 + lane * 8;
      unsigned short* dst = &Wbuf[half][bufIdx][plane][seg * 512];  // wave-uniform
      gload_lds16(src, dst);
    }
  };

  // precomputed per-lane B read offsets (shorts) into the pre-swizzled rows
  int xoff[4];
#pragma unroll
  for (int s4 = 0; s4 < 4; ++s4) xoff[s4] = ((2 * s4 + h) ^ (m & 7)) * 8;
  const int mrow = m * 64;
  const int cbase = hw * 4096;

#define RDH(BUF, I) (*(const short8*)&Wbuf[hw][(BUF)][0][mrow + xoff[(I)]])
#define RDL(BUF, I) (*(const short8*)&Wbuf[hw][(BUF)][1][mrow + xoff[(I)]])

  // ---- prologue: 2 stages of DMA, drain once, prime bh+bl <- stage 0 ----
  issueStage(0, 0);
  issueStage(1, 1);
  float cn_cur = cnf[cbase + m];
  asm volatile("s_waitcnt vmcnt(0)" ::: "memory");
  __builtin_amdgcn_s_barrier();
  asm volatile("" ::: "memory");

  short8 bh0 = RDH(0, 0), bh1 = RDH(0, 1), bh2 = RDH(0, 2), bh3 = RDH(0, 3);
  short8 bl0 = RDL(0, 0), bl1 = RDL(0, 1), bl2 = RDL(0, 2), bl3 = RDL(0, 3);

  for (int s = 0; s < 128; ++s) {
    // region s: issue exactly {2 DMA, 1 cnf} = 3 vm ops (branchless wrap
    // keeps the count uniform; tail DMAs land in dead buffers)
    issueStage((s + 2) & 127, (s + 2) & 3);
    const float cn_next = cnf[cbase + ((s + 1) & 127) * 32 + m];
    asm volatile("s_waitcnt vmcnt(3)" ::: "memory");
    __builtin_amdgcn_s_barrier();
    asm volatile("" ::: "memory");

    const int nb = (s + 1) & 3;

    floatx16 acc;
#pragma unroll
    for (int r = 0; r < 16; ++r) acc[r] = cn_cur;

    // pairwise plane products: bh_i dies after its 2 MFMAs -> its s+1
    // replacement read issues immediately (WAR-pinned, sprinkled through
    // the MFMA phase). bl_i dies after 1 MFMA; same pattern.
    acc = MFMA(ah[0], bh0, acc);
    acc = MFMA(al[0], bh0, acc);
    bh0 = RDH(nb, 0);
    acc = MFMA(ah[1], bh1, acc);
    acc = MFMA(al[1], bh1, acc);
    bh1 = RDH(nb, 1);
    acc = MFMA(ah[2], bh2, acc);
    acc = MFMA(al[2], bh2, acc);
    bh2 = RDH(nb, 2);
    acc = MFMA(ah[3], bh3, acc);
    acc = MFMA(al[3], bh3, acc);
    bh3 = RDH(nb, 3);
    acc = MFMA(ah[0], bl0, acc);
    bl0 = RDL(nb, 0);
    acc = MFMA(ah[1], bl1, acc);
    bl1 = RDL(nb, 1);
    acc = MFMA(ah[2], bl2, acc);
    bl2 = RDL(nb, 2);
    acc = MFMA(ah[3], bl3, acc);
    bl3 = RDL(nb, 3);

    // packed-key argmin: acc[r] > 0; low byte := stage id
#pragma unroll
    for (int r = 0; r < 16; ++r) {
      kmin[r] = fminf(kmin[r],
          __uint_as_float((__float_as_uint(acc[r]) & 0xFFFFFF00u) | (unsigned)s));
    }
    cn_cur = cn_next;
  }
#undef RDH
#undef RDL

  // ---- reduce over the 32 code-cols per row, carrying origin lane ----
#pragma unroll
  for (int r = 0; r < 16; ++r) {
    float kv = kmin[r];
    int mo = m;
#pragma unroll
    for (int mm = 1; mm < 32; mm <<= 1) {
      const float ov = __shfl_xor(kv, mm);
      const int   om = __shfl_xor(mo, mm);
      if (ov < kv || (ov == kv && om < mo)) { kv = ov; mo = om; }
    }
    // C/D layout: row = (r&3) + 8*(r>>2) + 4*h. One writer lane per row.
    const int mr = (r & 3) + 8 * (r >> 2) + 4 * h;
    if (m == mr) {
      const unsigned int kb = __float_as_uint(kv);
      tok_s[hw][tg * 32 + mr] = hw * 4096 + (int)(kb & 0xFFu) * 32 + mo;
      mind_s[hw][tg * 32 + mr] =
          __uint_as_float(kb & 0xFFFFFF00u) - 64.0f + znorm;
    }
  }
  __syncthreads();

  float* counts = ws + WS_COUNTS;
  float* embsum = ws + WS_EMBSUM;

  // merge code-halves (strict '<' keeps half0 on ties), qe partial + counts
  if (tid < 128) {
    const float d0 = mind_s[0][tid], d1 = mind_s[1][tid];
    const int   i0 = tok_s[0][tid],  i1 = tok_s[1][tid];
    const bool t1 = d1 < d0;
    const float dm = t1 ? d1 : d0;
    const int   im = t1 ? i1 : i0;
    tok_s[0][tid] = im;
    float qe = dm;
#pragma unroll
    for (int mm = 32; mm >= 1; mm >>= 1) qe += __shfl_xor(qe, mm);
    if ((tid & 63) == 0) atomicAdd(ws + WS_QE, qe);
    atomicAdd(&counts[im], 1.0f);
  }
  __syncthreads();

  // segment-sum of z: wave-coalesced atomics (64 consecutive floats/instr)
#pragma unroll 4
  for (int t = 0; t < 16; ++t) {
    const int row = w * 16 + t;
    const int tk = tok_s[0][row];
    const float zv = z[(size_t)(tb + row) * D_DIM + lane];
    atomicAdd(&embsum[(size_t)tk * D_DIM + lane], zv);
  }
}

// ---------------------------------------------------------------------------
// Fused finalize: n = 0.9*sum(cs) + 0.1*N_TOK is precomputed by vq_prep
// (sum(counts) == N_TOK exactly), so ncs/nea/weight all finalize in one pass.
__global__ void vq_finalize(const float* __restrict__ cluster_size,
                            const float* __restrict__ embed_avg,
                            const float* __restrict__ ws, float* __restrict__ out)
{
  const int idx = blockIdx.x * 256 + threadIdx.x;   // over K*D
  const int k = idx >> 6;
  const float ncs = cluster_size[k] * DECAY + OMD * ws[WS_COUNTS + k];
  const float nea = embed_avg[idx] * DECAY + OMD * ws[WS_EMBSUM + idx];
  out[OUT_EA + idx] = nea;
  float n = OMD * (float)N_TOK;
#pragma unroll
  for (int i = 0; i < 8; ++i) n += ws[WS_NSUM + (i << 5)];
  const float sm = (ncs + EPS) / (n + K_CODE * EPS) * n;
  out[OUT_W + idx] = nea / sm;
  if ((idx & 63) == 0) out[OUT_CS + k] = ncs;
  if (idx == 0) out[OUT_QE] = ws[WS_QE] * (1.0f / N_TOK);
}

// ---------------------------------------------------------------------------
extern "C" void kernel_launch(void* const* d_in, const int* in_sizes, int n_in,
                              void* d_out, int out_size, void* d_ws, size_t ws_size,
                              hipStream_t stream) {
  const float* z  = (const float*)d_in[0];
  const float* w  = (const float*)d_in[1];
  const float* cs = (const float*)d_in[2];
  const float* ea = (const float*)d_in[3];
  float* out = (float*)d_out;
  float* ws  = (float*)d_ws;

  // header only (QE + NSUM slots); counts/embsum zeroing folded into vq_prep
  (void)hipMemsetAsync(d_ws, 0, (size_t)WS_COUNTS * sizeof(float), stream);

  vq_prep<<<K_CODE / 4, 256, 0, stream>>>(w, cs, ws);
  vq_argmin<<<N_TOK / 128, 512, 0, stream>>>(z, ws);
  vq_finalize<<<K_CODE * D_DIM / 256, 256, 0, stream>>>(cs, ea, ws, out);
}